// Round 7
// baseline (527.525 us; speedup 1.0000x reference)
//
#include <hip/hip_runtime.h>
#include <hip/hip_bf16.h>

// GCN 2-layer forward on MI355X (gfx950). fp32 in/out, int32 edges.
// Round 11: delete k_gemm2 via GCN linearity (the proven half of round-8):
//   sum_s h2[s]*dinv[s] = (sum_s r1[s]*dinv[s]) @ W2^T
//   - gather1 now stores r1s = relu(...)*dinv (pre-scaled; round-8 verified
//     this numerically, absmax 9.8e-4 pass).
//   - gather2 gathers r1s rows (same 128B layout/traffic as h2s-padded) and
//     applies the 64->40 W2 matvec as an in-LDS per-node epilogue.
//   - k_gemm2 DELETED: launch gap + 12.8MB r1 re-read + 12.8MB h2s write gone.
// CSR build, gemm1, gather loop structure byte-identical to verified round-9
// source (500.0us). Harness poison-fills (~120us x N) dominate dur_us and are
// untouchable; remaining wins are whole-kernel deletions like this one.
// Round 12: identical resubmission (bench infra failed twice; no counters).

typedef __attribute__((ext_vector_type(8))) short bf16x8;   // 8 bf16 = 4 VGPRs
typedef __attribute__((ext_vector_type(4))) float f32x4;    // MFMA C/D

constexpr int NN = 100000;   // nodes
constexpr int NF = 512;      // input feats
constexpr int NH = 64;       // hidden
constexpr int NC = 40;       // classes
constexpr int NE = 1600000;  // edges

constexpr int NBUCK = 391;     // ceil(NN/256): bucket = dst >> 8
constexpr int CAP   = 6144;    // staging capacity/bucket (mean 4092, +32 sigma)
constexpr int ABLK  = 250;     // binA blocks
constexpr int CHUNK = NE / ABLK;  // 6400 edges/block (exact, /4 = 1600 int4)

// ---- ws layout (byte offsets) ----
constexpr size_t OFF_DINV   = 0;           // float[NN]
constexpr size_t OFF_ROWPTR = 524288;      // int[NN+1]
constexpr size_t OFF_GCUR   = 1048576;     // int[512] bucket totals (391 used)
constexpr size_t OFF_W1BF   = 1576960;     // bf16[64*512] = 64KB
constexpr size_t OFF_W2BF   = 1642496;     // bf16[40*64]
constexpr size_t OFF_EBUF   = 2097152;     // int[NE] CSR src ids, 6.4MB
constexpr size_t OFF_H1     = 9437184;     // bf16[NN*64] = 12.8MB
constexpr size_t OFF_R1     = 23068672;    // bf16[NN*64] = 12.8MB (r1s, pre-scaled)
// staging int[NBUCK*CAP] = 9.61MB ALIASES h1s region (dead during CSR build)
constexpr size_t OFF_STAGE  = OFF_H1;

// fp32 -> bf16 fragment helpers
__device__ inline short f2bs(float f) {
    union { __hip_bfloat16 h; short s; } u;
    u.h = __float2bfloat16(f);
    return u.s;
}
// vectorized: two 16B fp32 loads -> 8 bf16
__device__ inline bf16x8 cvt8v(const float* __restrict__ p) {
    const f32x4* q4 = reinterpret_cast<const f32x4*>(p);
    f32x4 a = q4[0], b = q4[1];
    bf16x8 r;
#pragma unroll
    for (int i = 0; i < 4; ++i) { r[i] = f2bs(a[i]); r[i + 4] = f2bs(b[i]); }
    return r;
}

// ---------------- W1/W2 fp32 -> bf16 (once) + zero bucket cursors ----------
__global__ __launch_bounds__(256) void k_cvtw(const float* __restrict__ W1,
                                              const float* __restrict__ W2,
                                              __hip_bfloat16* __restrict__ W1bf,
                                              __hip_bfloat16* __restrict__ W2bf,
                                              int* __restrict__ gcur) {
    int i = blockIdx.x * 256 + threadIdx.x;
    if (i < NH * NF) W1bf[i] = __float2bfloat16(W1[i]);
    int j = i - NH * NF;
    if (j >= 0 && j < NC * NH) W2bf[j] = __float2bfloat16(W2[j]);
    if (i < 512) gcur[i] = 0;
}

// ---------------- binA: bucket edges by dst>>8, int4 reads, packed writes ----
__global__ __launch_bounds__(256) void k_binA(const int* __restrict__ src,
                                              const int* __restrict__ dst,
                                              int* __restrict__ gcur,
                                              int* __restrict__ staging) {
    __shared__ int cnt[NBUCK];
    __shared__ int base[NBUCK];
    __shared__ int cur[NBUCK];
    const int t = threadIdx.x;
    const int e0 = blockIdx.x * CHUNK;
    for (int i = t; i < NBUCK; i += 256) { cnt[i] = 0; cur[i] = 0; }
    __syncthreads();
    const int4* d4 = reinterpret_cast<const int4*>(dst + e0);
    const int4* s4 = reinterpret_cast<const int4*>(src + e0);
    for (int g = t; g < CHUNK / 4; g += 256) {
        int4 d = d4[g];
        atomicAdd(&cnt[d.x >> 8], 1);
        atomicAdd(&cnt[d.y >> 8], 1);
        atomicAdd(&cnt[d.z >> 8], 1);
        atomicAdd(&cnt[d.w >> 8], 1);
    }
    __syncthreads();
    for (int i = t; i < NBUCK; i += 256)
        base[i] = atomicAdd(&gcur[i], cnt[i]);   // reserve contiguous run
    __syncthreads();
    for (int g = t; g < CHUNK / 4; g += 256) {
        int4 d = d4[g];
        int4 s = s4[g];
        {
            int b = d.x >> 8; int r = atomicAdd(&cur[b], 1); int pos = base[b] + r;
            if (pos < CAP) staging[b * CAP + pos] = ((d.x & 255) << 17) | s.x;
        }
        {
            int b = d.y >> 8; int r = atomicAdd(&cur[b], 1); int pos = base[b] + r;
            if (pos < CAP) staging[b * CAP + pos] = ((d.y & 255) << 17) | s.y;
        }
        {
            int b = d.z >> 8; int r = atomicAdd(&cur[b], 1); int pos = base[b] + r;
            if (pos < CAP) staging[b * CAP + pos] = ((d.z & 255) << 17) | s.z;
        }
        {
            int b = d.w >> 8; int r = atomicAdd(&cur[b], 1); int pos = base[b] + r;
            if (pos < CAP) staging[b * CAP + pos] = ((d.w & 255) << 17) | s.w;
        }
    }
}

// ---------------- binB: per-bucket prefix + degree/rowptr/dinv + CSR scatter ----
__global__ __launch_bounds__(256) void k_binB(const int* __restrict__ gcur,
                                              const int* __restrict__ staging,
                                              int* __restrict__ rowptr,
                                              float* __restrict__ dinv,
                                              int* __restrict__ ebuf) {
    __shared__ int redbuf[256];
    __shared__ int hist[256];
    __shared__ int s[256];
    __shared__ int cur[256];
    const int b = blockIdx.x, t = threadIdx.x;
    const int count = gcur[b];
    const int sbase = b * CAP;

    // fused exclusive-prefix: base = sum(gcur[0..b))
    int acc0 = 0;
    if (t < b) acc0 = gcur[t];
    if (t + 256 < b) acc0 += gcur[t + 256];
    redbuf[t] = acc0;
    hist[t] = 0;
    __syncthreads();
    for (int off = 128; off > 0; off >>= 1) {
        if (t < off) redbuf[t] += redbuf[t + off];
        __syncthreads();
    }
    const int base = redbuf[0];

    // in-bucket histogram (= per-node degree)
    for (int i = t; i < count; i += 256)
        atomicAdd(&hist[staging[sbase + i] >> 17], 1);
    __syncthreads();
    int v = hist[t];
    s[t] = v;
    __syncthreads();
    for (int off = 1; off < 256; off <<= 1) {
        int tv = (t >= off) ? s[t - off] : 0;
        __syncthreads();
        s[t] += tv;
        __syncthreads();
    }
    const int excl = s[t] - v;           // local exclusive offset
    int n = b * 256 + t;
    if (n < NN) {
        rowptr[n] = base + excl;
        dinv[n] = rsqrtf((float)v + 1.0f);   // +1 = self-loop
    }
    if (b == 0 && t == 0) rowptr[NN] = NE;
    cur[t] = excl;
    __syncthreads();
    for (int i = t; i < count; i += 256) {
        int pv = staging[sbase + i];
        int p = atomicAdd(&cur[pv >> 17], 1);
        ebuf[base + p] = pv & 0x1FFFF;   // src id
    }
}

// ---------------- GEMM1: h1s[NN,64] = (x @ W1^T) * dinv[row]  (bf16) ----
__global__ __launch_bounds__(256) void k_gemm1(const float* __restrict__ x,
                                               const __hip_bfloat16* __restrict__ W1bf,
                                               const float* __restrict__ dinv,
                                               __hip_bfloat16* __restrict__ h1s) {
    const int lane = threadIdx.x & 63;
    const int wave = blockIdx.x * 4 + (threadIdx.x >> 6);
    const int row0 = wave * 32;
    if (row0 >= NN) return;
    const int q = lane >> 4, m = lane & 15;

    f32x4 acc[2][4];
#pragma unroll
    for (int i = 0; i < 2; ++i)
#pragma unroll
        for (int j = 0; j < 4; ++j) acc[i][j] = (f32x4){0.f, 0.f, 0.f, 0.f};

    for (int k0 = 0; k0 < NF; k0 += 32) {
        bf16x8 bfr[4];
#pragma unroll
        for (int ot = 0; ot < 4; ++ot)
            bfr[ot] = *reinterpret_cast<const bf16x8*>(W1bf + (ot * 16 + m) * NF + k0 + q * 8);
#pragma unroll
        for (int mt = 0; mt < 2; ++mt) {
            int r = row0 + mt * 16 + m;
            if (r > NN - 1) r = NN - 1;  // tail clamp (store guarded)
            bf16x8 afr = cvt8v(x + (size_t)r * NF + k0 + q * 8);
#pragma unroll
            for (int ot = 0; ot < 4; ++ot)
                acc[mt][ot] = __builtin_amdgcn_mfma_f32_16x16x32_bf16(afr, bfr[ot], acc[mt][ot], 0, 0, 0);
        }
    }

#pragma unroll
    for (int mt = 0; mt < 2; ++mt)
#pragma unroll
        for (int rr = 0; rr < 4; ++rr) {
            int row = row0 + mt * 16 + q * 4 + rr;
            if (row < NN) {
                float di = dinv[row];
#pragma unroll
                for (int ot = 0; ot < 4; ++ot)
                    h1s[row * NH + ot * 16 + m] = __float2bfloat16(acc[mt][ot][rr] * di);
            }
        }
}

// ---------------- gather1: r1s[n] = relu(dn*(sum h1s[s]+h1s[n]) + b1)*dn ----
// (pre-scaled by dinv so layer 2 can aggregate r1s directly)
__global__ __launch_bounds__(256) void k_gather1(const int* __restrict__ rowptr,
                                                 const int* __restrict__ ebuf,
                                                 const float* __restrict__ dinv,
                                                 const __hip_bfloat16* __restrict__ h1s,
                                                 const float* __restrict__ b1,
                                                 __hip_bfloat16* __restrict__ r1s) {
    const int lane = threadIdx.x & 63;
    const int n = blockIdx.x * 4 + (threadIdx.x >> 6);
    if (n >= NN) return;
    const int beg = rowptr[n], end = rowptr[n + 1];
    // independent loads issued early: self-loop row + bias + dinv
    float selfv = __bfloat162float(h1s[n * NH + lane]);
    float bias = b1[lane];
    float dn = dinv[n];
    float acc = 0.0f;
    int j = beg;
    for (; j + 8 <= end; j += 8) {
        int e0 = ebuf[j + 0], e1 = ebuf[j + 1], e2 = ebuf[j + 2], e3 = ebuf[j + 3];
        int e4 = ebuf[j + 4], e5 = ebuf[j + 5], e6 = ebuf[j + 6], e7 = ebuf[j + 7];
        float v0 = __bfloat162float(h1s[e0 * NH + lane]);
        float v1 = __bfloat162float(h1s[e1 * NH + lane]);
        float v2 = __bfloat162float(h1s[e2 * NH + lane]);
        float v3 = __bfloat162float(h1s[e3 * NH + lane]);
        float v4 = __bfloat162float(h1s[e4 * NH + lane]);
        float v5 = __bfloat162float(h1s[e5 * NH + lane]);
        float v6 = __bfloat162float(h1s[e6 * NH + lane]);
        float v7 = __bfloat162float(h1s[e7 * NH + lane]);
        acc += ((v0 + v1) + (v2 + v3)) + ((v4 + v5) + (v6 + v7));
    }
    for (; j < end; ++j)
        acc += __bfloat162float(h1s[ebuf[j] * NH + lane]);
    acc += selfv;   // self-loop (pre-scaled)
    acc = acc * dn + bias;
    r1s[n * NH + lane] = __float2bfloat16(fmaxf(acc, 0.0f) * dn);
}

// ---------------- gather2: out[n] = dn*((sum r1s[s] + r1s[n]) @ W2^T) + b2 ----
// Aggregates r1s rows, then 64->40 matvec in LDS per node. No gemm2, no h2s.
__global__ __launch_bounds__(256) void k_gather2(const int* __restrict__ rowptr,
                                                 const int* __restrict__ ebuf,
                                                 const float* __restrict__ dinv,
                                                 const __hip_bfloat16* __restrict__ r1s,
                                                 const __hip_bfloat16* __restrict__ W2bf,
                                                 const float* __restrict__ b2,
                                                 float* __restrict__ out) {
    __shared__ float W2l[40 * 65];    // pad-65: (c*65+k)%32=(c+k)%32, 2-way free
    __shared__ float accL[4 * 64];    // one 64-float row per wave
    const int t = threadIdx.x;
    for (int i = t; i < NC * NH; i += 256)
        W2l[(i >> 6) * 65 + (i & 63)] = __bfloat162float(W2bf[i]);
    __syncthreads();                  // all 256 threads alive (NN % 4 == 0)

    const int lane = t & 63, w = t >> 6;
    const int n = blockIdx.x * 4 + w;
    if (n >= NN) return;              // never taken: NN divisible by 4
    const int beg = rowptr[n], end = rowptr[n + 1];
    float selfv = __bfloat162float(r1s[n * NH + lane]);
    float dn = dinv[n];
    float acc = 0.0f;
    int j = beg;
    for (; j + 8 <= end; j += 8) {
        int e0 = ebuf[j + 0], e1 = ebuf[j + 1], e2 = ebuf[j + 2], e3 = ebuf[j + 3];
        int e4 = ebuf[j + 4], e5 = ebuf[j + 5], e6 = ebuf[j + 6], e7 = ebuf[j + 7];
        float v0 = __bfloat162float(r1s[e0 * NH + lane]);
        float v1 = __bfloat162float(r1s[e1 * NH + lane]);
        float v2 = __bfloat162float(r1s[e2 * NH + lane]);
        float v3 = __bfloat162float(r1s[e3 * NH + lane]);
        float v4 = __bfloat162float(r1s[e4 * NH + lane]);
        float v5 = __bfloat162float(r1s[e5 * NH + lane]);
        float v6 = __bfloat162float(r1s[e6 * NH + lane]);
        float v7 = __bfloat162float(r1s[e7 * NH + lane]);
        acc += ((v0 + v1) + (v2 + v3)) + ((v4 + v5) + (v6 + v7));
    }
    for (; j < end; ++j)
        acc += __bfloat162float(r1s[ebuf[j] * NH + lane]);
    acc += selfv;   // self-loop (pre-scaled)

    // per-wave matvec epilogue: out[c] = dn * sum_k acc[k]*W2[c][k] + b2[c]
    accL[w * 64 + lane] = acc;
    __threadfence_block();            // order LDS write -> cross-lane read (in-wave)
    if (lane < NC) {
        const float* av = &accL[w * 64];
        const float* Wr = &W2l[lane * 65];
        float o = 0.f;
#pragma unroll
        for (int k = 0; k < 64; ++k)
            o += av[k] * Wr[k];
        out[n * NC + lane] = o * dn + b2[lane];
    }
}

extern "C" void kernel_launch(void* const* d_in, const int* in_sizes, int n_in,
                              void* d_out, int out_size, void* d_ws, size_t ws_size,
                              hipStream_t stream) {
    const float* x  = (const float*)d_in[0];
    const int*   ei = (const int*)d_in[1];
    const float* W1 = (const float*)d_in[2];
    const float* b1 = (const float*)d_in[3];
    const float* W2 = (const float*)d_in[4];
    const float* b2 = (const float*)d_in[5];
    const int* srcp = ei;        // edge_index[0]
    const int* dstp = ei + NE;   // edge_index[1]

    char* ws = (char*)d_ws;
    float*          dinv    = (float*)(ws + OFF_DINV);
    int*            rowptr  = (int*)(ws + OFF_ROWPTR);
    int*            gcur    = (int*)(ws + OFF_GCUR);
    __hip_bfloat16* W1bf    = (__hip_bfloat16*)(ws + OFF_W1BF);
    __hip_bfloat16* W2bf    = (__hip_bfloat16*)(ws + OFF_W2BF);
    int*            ebuf    = (int*)(ws + OFF_EBUF);
    int*            staging = (int*)(ws + OFF_STAGE);          // aliases h1s
    __hip_bfloat16* h1s     = (__hip_bfloat16*)(ws + OFF_H1);
    __hip_bfloat16* r1s     = (__hip_bfloat16*)(ws + OFF_R1);

    // --- weights to bf16 + zero bucket cursors ---
    k_cvtw<<<(NH * NF + NC * NH + 255) / 256, 256, 0, stream>>>(W1, W2, W1bf, W2bf, gcur);

    // --- CSR build: two-level bucket sort (staging aliases h1s, dead here) ---
    k_binA<<<ABLK, 256, 0, stream>>>(srcp, dstp, gcur, staging);
    k_binB<<<NBUCK, 256, 0, stream>>>(gcur, staging, rowptr, dinv, ebuf);

    const int g1_blocks = ((NN + 31) / 32 + 3) / 4;   // 782: 4 waves, 32 rows/wave
    const int node_blocks = (NN + 3) / 4;             // 4 waves/block, 1 node/wave

    // --- layer 1 ---
    k_gemm1<<<g1_blocks, 256, 0, stream>>>(x, W1bf, dinv, h1s);
    k_gather1<<<node_blocks, 256, 0, stream>>>(rowptr, ebuf, dinv, h1s, b1, r1s);

    // --- layer 2: aggregation + fused 64->40 matvec (gemm2 deleted) ---
    k_gather2<<<node_blocks, 256, 0, stream>>>(rowptr, ebuf, dinv, r1s, W2bf, b2,
                                               (float*)d_out);
}